// Round 21
// baseline (854.849 us; speedup 1.0000x reference)
//
#include <hip/hip_runtime.h>
#include <stdint.h>

#define N_ROWS 32768
#define N_E    4096
#define E_DIM  256

typedef __attribute__((ext_vector_type(8))) short short8;
typedef __attribute__((ext_vector_type(4))) float f32x4;

// sortable-uint encoding: order-preserving float -> uint
__device__ __forceinline__ unsigned int f2sort(float s) {
    unsigned int b = __float_as_uint(s);
    return (b & 0x80000000u) ? ~b : (b | 0x80000000u);
}
__device__ __forceinline__ float sort2f(unsigned int u) {
    unsigned int b = (u & 0x80000000u) ? (u ^ 0x80000000u) : ~u;
    return __uint_as_float(b);
}
__device__ __forceinline__ unsigned short bfr(float x) {   // f32 -> bf16 RNE
    unsigned int u = __float_as_uint(x);
    return (unsigned short)((u + 0x7fffu + ((u >> 16) & 1u)) >> 16);
}
__device__ __forceinline__ float bf2f(unsigned short h) {
    return __uint_as_float((unsigned int)h << 16);
}

// ---------- kernel 1: f32 row norms (f64 accumulate, cast f32) ----------
__global__ __launch_bounds__(256) void k_rownorm(const float* __restrict__ src,
                                                 float* __restrict__ outf) {
    int j = blockIdx.x * 4 + (threadIdx.x >> 6);
    int lane = threadIdx.x & 63;
    const float4* e4 = (const float4*)(src + (size_t)j * E_DIM);
    float4 v = e4[lane];
    double s = (double)v.x * v.x + (double)v.y * v.y + (double)v.z * v.z + (double)v.w * v.w;
    #pragma unroll
    for (int off = 1; off < 64; off <<= 1) s += __shfl_xor(s, off);
    if (lane == 0) outf[j] = (float)s;
}

// ---------- kernel 2: bf16 hi/lo split into MFMA fragment-major layout (emb) ----------
__global__ __launch_bounds__(256) void k_split(const float* __restrict__ src,
                                               unsigned short* __restrict__ hi,
                                               unsigned short* __restrict__ lo) {
    int c = blockIdx.x * 256 + threadIdx.x;   // 8-float chunk id
    int r   = c >> 5;
    int kc8 = c & 31;
    const float* p = src + (size_t)c * 8;
    float v[8];
    *(float4*)&v[0] = *(const float4*)p;
    *(float4*)&v[4] = *(const float4*)(p + 4);
    short8 h8, l8;
    #pragma unroll
    for (int t = 0; t < 8; t++) {
        unsigned short h = bfr(v[t]);
        h8[t] = (short)h;
        l8[t] = (short)bfr(v[t] - bf2f(h));
    }
    int kt = kc8 >> 2, lg = kc8 & 3;
    size_t o8 = (size_t)(r >> 4) * 512 + kt * 64 + lg * 16 + (r & 15);
    *(short8*)(hi + o8 * 8) = h8;
    *(short8*)(lo + o8 * 8) = l8;
}

// ---------- kernel 3: screener, B DIRECT FROM L2 (no LDS) + fused zero-fill ----------
// r14 proved B (4 MB = per-XCD L2) stays L2-resident once the z stream is
// gone (FETCH 33 MB); r7's direct-read failure was z-stream eviction, not
// the read path. Reading B fragments straight from L2 deletes all barriers,
// staging, and the ds_read->MFMA chain (r15/16: ~150 us exposed latency at
// 1 wave/SIMD). Waves fully independent; compiler pipelines vmcnt freely.
__global__ __launch_bounds__(256, 1) void k_screen(
        const float* __restrict__ z,
        const unsigned short* __restrict__ ehi, const unsigned short* __restrict__ elo,
        const float* __restrict__ enf, const float* __restrict__ znf,
        int* __restrict__ idx, int* __restrict__ flaglist, int* __restrict__ flagcnt,
        float* __restrict__ out) {
    const int tid  = threadIdx.x;
    const int lane = tid & 63;
    const int w    = tid >> 6;                 // wave 0..3
    const int l15  = lane & 15;
    const int lg   = lane >> 4;
    const int fb0  = blockIdx.x * 8 + w * 2;   // wave's first 16-row frag block

    const short8* Gh = (const short8*)ehi;
    const short8* Gl = (const short8*)elo;
    float* zfill = out + (size_t)blockIdx.x * 524288;   // zero region [0,134217728)

    // ---- prologue: read z rows, split hi/lo in-register -> A-frags (once) ----
    short8 ah[2][8], al[2][8];
    #pragma unroll
    for (int mi = 0; mi < 2; mi++) {
        int row = (fb0 + mi) * 16 + l15;
        const float* zr = z + (size_t)row * E_DIM + lg * 8;
        #pragma unroll
        for (int kt = 0; kt < 8; kt++) {
            float4 v0 = *(const float4*)(zr + kt * 32);
            float4 v1 = *(const float4*)(zr + kt * 32 + 4);
            float v[8] = {v0.x, v0.y, v0.z, v0.w, v1.x, v1.y, v1.z, v1.w};
            short8 h8, l8;
            #pragma unroll
            for (int t = 0; t < 8; t++) {
                unsigned short h = bfr(v[t]);
                h8[t] = (short)h;
                l8[t] = (short)bfr(v[t] - bf2f(h));
            }
            ah[mi][kt] = h8;
            al[mi][kt] = l8;
        }
    }

    float czs[8];
    #pragma unroll
    for (int mi = 0; mi < 2; mi++)
        #pragma unroll
        for (int qi = 0; qi < 4; qi++)
            czs[mi * 4 + qi] = znf[(fb0 + mi) * 16 + lg * 4 + qi];

    unsigned long long K1[8];
    float Qf[8];
    #pragma unroll
    for (int s = 0; s < 8; s++) { K1[s] = ~0ull; Qf[s] = __uint_as_float(0x7F800000u); }

// load B fragments for kt directly from L2 (frag-major, 1KB coalesced/wave)
#define LOADB(BH, BL, KT)                                                     \
    _Pragma("unroll")                                                         \
    for (int p = 0; p < 4; p++) {                                             \
        BH[p] = Gh[(size_t)(t * 4 + p) * 512 + (KT) * 64 + lane];             \
        BL[p] = Gl[(size_t)(t * 4 + p) * 512 + (KT) * 64 + lane];             \
    }
#define DOMFMA(BH, BL, KT)                                                    \
    _Pragma("unroll")                                                         \
    for (int p = 0; p < 4; p++) {                                             \
        _Pragma("unroll")                                                     \
        for (int mi = 0; mi < 2; mi++) {                                      \
            acc[mi][p] = __builtin_amdgcn_mfma_f32_16x16x32_bf16(ah[mi][KT], BH[p], acc[mi][p], 0, 0, 0); \
            acc[mi][p] = __builtin_amdgcn_mfma_f32_16x16x32_bf16(al[mi][KT], BH[p], acc[mi][p], 0, 0, 0); \
            acc[mi][p] = __builtin_amdgcn_mfma_f32_16x16x32_bf16(ah[mi][KT], BL[p], acc[mi][p], 0, 0, 0); \
        }                                                                     \
    }

    for (int t = 0; t < 64; ++t) {
        // ---- fused one-hot zero-fill: 32 KB/block/tile on the idle write path
        {
            f32x4 zv4 = {0.f, 0.f, 0.f, 0.f};
            float* dst = zfill + (size_t)t * 8192 + tid * 4;
            #pragma unroll
            for (int i = 0; i < 8; i++)
                __builtin_nontemporal_store(zv4, (f32x4*)(dst + i * 1024));
        }

        f32x4 acc[2][4];
        #pragma unroll
        for (int mi = 0; mi < 2; mi++)
            #pragma unroll
            for (int p = 0; p < 4; p++)
                acc[mi][p] = (f32x4){0.f, 0.f, 0.f, 0.f};

        // 2-deep kt pipeline: kt+1/kt+2 loads fly under kt's 24 MFMAs
        short8 bhA[4], blA[4], bhB[4], blB[4];
        LOADB(bhA, blA, 0)
        LOADB(bhB, blB, 1)
        DOMFMA(bhA, blA, 0) LOADB(bhA, blA, 2)
        DOMFMA(bhB, blB, 1) LOADB(bhB, blB, 3)
        DOMFMA(bhA, blA, 2) LOADB(bhA, blA, 4)
        DOMFMA(bhB, blB, 3) LOADB(bhB, blB, 5)
        DOMFMA(bhA, blA, 4) LOADB(bhA, blA, 6)
        DOMFMA(bhB, blB, 5) LOADB(bhB, blB, 7)
        DOMFMA(bhA, blA, 6)
        DOMFMA(bhB, blB, 7)

        #pragma unroll
        for (int p = 0; p < 4; p++) {
            int j = t * 64 + p * 16 + l15;
            float Ce = enf[j];
            #pragma unroll
            for (int mi = 0; mi < 2; mi++) {
                #pragma unroll
                for (int qi = 0; qi < 4; qi++) {
                    int s = mi * 4 + qi;
                    float av = acc[mi][p][qi];
                    float A  = czs[s] + Ce;                 // fl32(Cz+Ce)
                    float qv = fmaf(-2.0f, av, A);          // fl32(A-2acc)
                    unsigned long long kk =
                        ((unsigned long long)f2sort(qv) << 32) | (unsigned int)j;
                    if (kk < K1[s]) K1[s] = kk;
                    float res = (A - qv) - 2.0f * av;       // exact rounding residue
                    float u = __uint_as_float(__float_as_uint(qv) & 0x7F800000u)
                              * 1.1920929e-7f;              // ulp(qv)
                    if (fabsf(res) > fmaf(0.5f, u, -1.5e-7f))
                        Qf[s] = fminf(Qf[s], qv);
                }
            }
        }
    }
#undef LOADB
#undef DOMFMA

    #pragma unroll
    for (int s = 0; s < 8; s++) {
        unsigned long long K = K1[s];
        float Q = Qf[s];
        #pragma unroll
        for (int off = 1; off < 16; off <<= 1) {
            unsigned long long ok = __shfl_xor(K, off);
            float oq = __shfl_xor(Q, off);
            if (ok < K) K = ok;
            Q = fminf(Q, oq);
        }
        if (l15 == 0) {
            int row = blockIdx.x * 128 + w * 32 + (s >> 2) * 16 + lg * 4 + (s & 3);
            idx[row] = (int)(K & 0xFFFFFFFFull);
            float qwin = sort2f((unsigned int)(K >> 32));
            float u = __uint_as_float(__float_as_uint(qwin) & 0x7F800000u) * 1.1920929e-7f;
            if (Q <= fmaf(2.0f, u, qwin)) {    // fragile candidate within 2 grid steps
                int pp = atomicAdd(flagcnt, 1);
                flaglist[pp] = row;
            }
        }
    }
}

// ---------- kernel 4: exact np-replica repair, j-QUARTERED ----------
// ascending-k single-acc f32 fma chain; q = fl32(fl32(Cz+Ce) - 2*acc).
__global__ __launch_bounds__(256) void k_repair(const float* __restrict__ z,
                                                const float* __restrict__ emb,
                                                const float* __restrict__ enf,
                                                const float* __restrict__ znf,
                                                const int* __restrict__ flagcnt,
                                                const int* __restrict__ flaglist,
                                                unsigned long long* __restrict__ kpart) {
    __shared__ float zr[8][E_DIM];
    __shared__ unsigned long long redk[4][8];   // [wave][row]
    const int tid = threadIdx.x;
    const int cnt = flagcnt[0];
    const int oct = blockIdx.x >> 2;            // 0..255
    const int qd  = blockIdx.x & 3;             // j-quarter

    for (int base = oct * 8; base < cnt; base += 2048) {
        __syncthreads();                         // protect zr/redk reuse
        int gr[8];
        #pragma unroll
        for (int r = 0; r < 8; r++) {
            int fi = base + r;
            gr[r] = flaglist[fi < cnt ? fi : base];
        }
        for (int i = tid; i < 8 * 64; i += 256) {
            int r = i >> 6, c4 = i & 63;
            *(float4*)&zr[r][c4 * 4] = *(const float4*)(z + (size_t)gr[r] * E_DIM + c4 * 4);
        }
        __syncthreads();

        float Cz[8];
        #pragma unroll
        for (int r = 0; r < 8; r++) Cz[r] = znf[gr[r]];

        unsigned long long bk[8];
        #pragma unroll
        for (int r = 0; r < 8; r++) bk[r] = ~0ull;

        #pragma unroll
        for (int g = 0; g < 2; g++) {
            const int j0 = qd * 1024 + g * 512 + tid;   // streams j0, j0+256
            const float* e0 = emb + (size_t)(j0      ) * E_DIM;
            const float* e1 = emb + (size_t)(j0 + 256) * E_DIM;
            float a[8][2];
            #pragma unroll
            for (int r = 0; r < 8; r++) { a[r][0] = 0.0f; a[r][1] = 0.0f; }

            #pragma unroll 4
            for (int k4 = 0; k4 < 64; k4++) {
                float4 v0 = *(const float4*)(e0 + k4 * 4);
                float4 v1 = *(const float4*)(e1 + k4 * 4);
                #pragma unroll
                for (int r = 0; r < 8; r++) {
                    float4 zq = *(const float4*)&zr[r][k4 * 4];
                    a[r][0] = fmaf(zq.x, v0.x, a[r][0]); a[r][0] = fmaf(zq.y, v0.y, a[r][0]);
                    a[r][0] = fmaf(zq.z, v0.z, a[r][0]); a[r][0] = fmaf(zq.w, v0.w, a[r][0]);
                    a[r][1] = fmaf(zq.x, v1.x, a[r][1]); a[r][1] = fmaf(zq.y, v1.y, a[r][1]);
                    a[r][1] = fmaf(zq.z, v1.z, a[r][1]); a[r][1] = fmaf(zq.w, v1.w, a[r][1]);
                }
            }
            float en0 = enf[j0], en1 = enf[j0 + 256];
            #pragma unroll
            for (int r = 0; r < 8; r++) {
                float q0 = (Cz[r] + en0) - 2.0f * a[r][0];
                float q1 = (Cz[r] + en1) - 2.0f * a[r][1];
                unsigned long long k;
                k = ((unsigned long long)f2sort(q0) << 32) | (unsigned int)(j0      ); if (k < bk[r]) bk[r] = k;
                k = ((unsigned long long)f2sort(q1) << 32) | (unsigned int)(j0 + 256); if (k < bk[r]) bk[r] = k;
            }
        }

        const int w = tid >> 6;
        #pragma unroll
        for (int r = 0; r < 8; r++) {
            unsigned long long K = bk[r];
            #pragma unroll
            for (int off = 1; off < 64; off <<= 1) {
                unsigned long long ok = __shfl_xor(K, off);
                if (ok < K) K = ok;
            }
            if ((tid & 63) == 0) redk[w][r] = K;
        }
        __syncthreads();
        if (tid < 8 && base + tid < cnt) {
            unsigned long long K = redk[0][tid];
            #pragma unroll
            for (int wv = 1; wv < 4; wv++)
                if (redk[wv][tid] < K) K = redk[wv][tid];
            kpart[(size_t)(base + tid) * 4 + qd] = K;
        }
    }
}

// ---------- kernel 5: reduce j-quarters -> idx ----------
__global__ __launch_bounds__(256) void k_fin(const int* __restrict__ flagcnt,
                                             const int* __restrict__ flaglist,
                                             const unsigned long long* __restrict__ kpart,
                                             int* __restrict__ idx) {
    const int cnt = flagcnt[0];
    for (int fi = blockIdx.x * 256 + threadIdx.x; fi < cnt; fi += gridDim.x * 256) {
        unsigned long long K = kpart[(size_t)fi * 4];
        #pragma unroll
        for (int qd = 1; qd < 4; qd++) {
            unsigned long long k2 = kpart[(size_t)fi * 4 + qd];
            if (k2 < K) K = k2;
        }
        idx[flaglist[fi]] = (int)(K & 0xFFFFFFFFull);
    }
}

// ---------- kernel 6: epilogue (zeros already written by k_screen) ----------
// d_out FLOAT32: [loss(1) | one-hot(32768*4096) | z_q_st(32768*256) |
//                 emb(4096*256) | indices(32768)]
__global__ __launch_bounds__(256) void k_epilogue(const float* __restrict__ z,
                                                  const float* __restrict__ emb,
                                                  const int* __restrict__ idx,
                                                  float* __restrict__ out,
                                                  double* __restrict__ rowloss) {
    const int row  = blockIdx.x * 4 + (threadIdx.x >> 6);
    const int lane = threadIdx.x & 63;
    const int j    = idx[row];
    float4 zv = *(const float4*)(z   + (size_t)row * E_DIM + lane * 4);
    float4 ev = *(const float4*)(emb + (size_t)j   * E_DIM + lane * 4);

    // z_q_st = fl32(z + fl32(z_q - z))
    float4 st;
    st.x = zv.x + (ev.x - zv.x);
    st.y = zv.y + (ev.y - zv.y);
    st.z = zv.z + (ev.z - zv.z);
    st.w = zv.w + (ev.w - zv.w);
    const size_t zq0 = 1ull + (size_t)N_ROWS * N_E;
    *(float4*)(out + zq0 + (size_t)row * E_DIM + lane * 4) = st;

    double dx = (double)ev.x - zv.x, dy = (double)ev.y - zv.y;
    double dz = (double)ev.z - zv.z, dw = (double)ev.w - zv.w;
    double s = dx * dx + dy * dy + dz * dz + dw * dw;
    #pragma unroll
    for (int off = 1; off < 64; off <<= 1) s += __shfl_xor(s, off);

    if (lane == 0) {
        rowloss[row] = s;
        // screen zeroed floats [0,134217728); the last one-hot cell
        // (row 32767, col 4095) sits at 134217728 -> cover it here.
        if (row == N_ROWS - 1 && j != N_E - 1)
            out[1ull + (size_t)row * N_E + (N_E - 1)] = 0.0f;
        out[1ull + (size_t)row * N_E + j] = 1.0f;
        const size_t ix0 = 1ull + (size_t)N_ROWS * N_E + (size_t)N_ROWS * E_DIM
                         + (size_t)N_E * E_DIM;
        out[ix0 + row] = (float)j;
    }
}

// ---------- kernel 7: deterministic loss reduce ----------
__global__ __launch_bounds__(256) void k_loss(const double* __restrict__ rowloss,
                                              float* __restrict__ out) {
    __shared__ double sm[256];
    double s = 0.0;
    for (int i = threadIdx.x; i < N_ROWS; i += 256) s += rowloss[i];
    sm[threadIdx.x] = s;
    __syncthreads();
    for (int h = 128; h > 0; h >>= 1) {
        if (threadIdx.x < h) sm[threadIdx.x] += sm[threadIdx.x + h];
        __syncthreads();
    }
    if (threadIdx.x == 0)
        out[0] = (float)(sm[0] / ((double)N_ROWS * (double)E_DIM));
}

extern "C" void kernel_launch(void* const* d_in, const int* in_sizes, int n_in,
                              void* d_out, int out_size, void* d_ws, size_t ws_size,
                              hipStream_t stream) {
    const float* z   = (const float*)d_in[0];
    const float* emb = (const float*)d_in[1];
    float* out = (float*)d_out;

    // workspace layout (disjoint, 16B-aligned)
    char* ws = (char*)d_ws;
    float*              enf      = (float*)(ws + 0);                 // 16 KB  -> 16384
    float*              znf      = (float*)(ws + 16384);             // 128 KB -> 147456
    int*                idx      = (int*)(ws + 147456);              // 128 KB -> 278528
    int*                flagcnt  = (int*)(ws + 278528);              // 128 B  -> 278656
    int*                flaglist = (int*)(ws + 278656);              // 128 KB -> 409728
    double*             rowloss  = (double*)(ws + 409728);           // 256 KB -> 671872
    unsigned long long* kpart    = (unsigned long long*)(ws + 671872);// 1 MB  -> 1720320
    unsigned short*     ehi      = (unsigned short*)(ws + 1720320);  // 2 MB   -> 3817472
    unsigned short*     elo      = (unsigned short*)(ws + 3817472);  // 2 MB   -> 5914624

    hipMemsetAsync(flagcnt, 0, sizeof(int), stream);

    // emb passthrough chunk: exact d2d copy
    const size_t emb0 = 1ull + (size_t)N_ROWS * N_E + (size_t)N_ROWS * E_DIM;
    hipMemcpyAsync(out + emb0, emb, (size_t)N_E * E_DIM * sizeof(float),
                   hipMemcpyDeviceToDevice, stream);

    k_rownorm <<<N_E / 4, 256, 0, stream>>>(emb, enf);
    k_rownorm <<<N_ROWS / 4, 256, 0, stream>>>(z, znf);
    k_split   <<<N_E / 8, 256, 0, stream>>>(emb, ehi, elo);
    k_screen  <<<256, 256, 0, stream>>>(z, ehi, elo, enf, znf,
                                        idx, flaglist, flagcnt, out);
    k_repair  <<<1024, 256, 0, stream>>>(z, emb, enf, znf, flagcnt, flaglist, kpart);
    k_fin     <<<32, 256, 0, stream>>>(flagcnt, flaglist, kpart, idx);
    k_epilogue<<<N_ROWS / 4, 256, 0, stream>>>(z, emb, idx, out, rowloss);
    k_loss    <<<1, 256, 0, stream>>>(rowloss, out);
}

// Round 22
// 371.113 us; speedup vs baseline: 2.3035x; 2.3035x over previous
//
#include <hip/hip_runtime.h>
#include <stdint.h>

#define N_ROWS 32768
#define N_E    4096
#define E_DIM  256

typedef __attribute__((ext_vector_type(8))) short short8;
typedef __attribute__((ext_vector_type(4))) float f32x4;

// async global->LDS 16B: dest = wave-uniform LDS base + lane*16
#define GLOAD_LDS16(g, l)                                                     \
    __builtin_amdgcn_global_load_lds(                                         \
        (const __attribute__((address_space(1))) void*)(g),                   \
        (__attribute__((address_space(3))) void*)(l), 16, 0, 0)

// sortable-uint encoding: order-preserving float -> uint
__device__ __forceinline__ unsigned int f2sort(float s) {
    unsigned int b = __float_as_uint(s);
    return (b & 0x80000000u) ? ~b : (b | 0x80000000u);
}
__device__ __forceinline__ float sort2f(unsigned int u) {
    unsigned int b = (u & 0x80000000u) ? (u ^ 0x80000000u) : ~u;
    return __uint_as_float(b);
}
__device__ __forceinline__ unsigned short bfr(float x) {   // f32 -> bf16 RNE
    unsigned int u = __float_as_uint(x);
    return (unsigned short)((u + 0x7fffu + ((u >> 16) & 1u)) >> 16);
}
__device__ __forceinline__ float bf2f(unsigned short h) {
    return __uint_as_float((unsigned int)h << 16);
}

// ---------- kernel 1: f32 row norms (f64 accumulate, cast f32) ----------
__global__ __launch_bounds__(256) void k_rownorm(const float* __restrict__ src,
                                                 float* __restrict__ outf) {
    int j = blockIdx.x * 4 + (threadIdx.x >> 6);
    int lane = threadIdx.x & 63;
    const float4* e4 = (const float4*)(src + (size_t)j * E_DIM);
    float4 v = e4[lane];
    double s = (double)v.x * v.x + (double)v.y * v.y + (double)v.z * v.z + (double)v.w * v.w;
    #pragma unroll
    for (int off = 1; off < 64; off <<= 1) s += __shfl_xor(s, off);
    if (lane == 0) outf[j] = (float)s;
}

// ---------- kernel 2: bf16 hi/lo split into MFMA fragment-major layout (emb) ----------
__global__ __launch_bounds__(256) void k_split(const float* __restrict__ src,
                                               unsigned short* __restrict__ hi,
                                               unsigned short* __restrict__ lo) {
    int c = blockIdx.x * 256 + threadIdx.x;   // 8-float chunk id
    int r   = c >> 5;
    int kc8 = c & 31;
    const float* p = src + (size_t)c * 8;
    float v[8];
    *(float4*)&v[0] = *(const float4*)p;
    *(float4*)&v[4] = *(const float4*)(p + 4);
    short8 h8, l8;
    #pragma unroll
    for (int t = 0; t < 8; t++) {
        unsigned short h = bfr(v[t]);
        h8[t] = (short)h;
        l8[t] = (short)bfr(v[t] - bf2f(h));
    }
    int kt = kc8 >> 2, lg = kc8 & 3;
    size_t o8 = (size_t)(r >> 4) * 512 + kt * 64 + lg * 16 + (r & 15);
    *(short8*)(hi + o8 * 8) = h8;
    *(short8*)(lo + o8 * 8) = l8;
}

// ---------- kernel 3: screener, 2 blocks/CU (decoupled barrier domains) ----------
// r21 refuted direct-L2 (latency-bound, 732 us) but proved B stays L2-resident
// (FETCH 33 MB). r18's stall model: one block-wide barrier re-syncs 4 waves
// every tile -> straggler stalls all. Here: 128-thr blocks (2 waves x 32
// rows), 64 KB LDS (dbuf 32-j tiles), grid 512 -> 2 independent blocks/CU.
// Same 16 MB/CU LDS traffic (register-capped invariant), but blocks de-phase
// so one block computes while the other drains its stage barrier.
__global__ __launch_bounds__(128, 1) void k_screen(
        const float* __restrict__ z,
        const unsigned short* __restrict__ ehi, const unsigned short* __restrict__ elo,
        const float* __restrict__ enf, const float* __restrict__ znf,
        int* __restrict__ idx, int* __restrict__ flaglist, int* __restrict__ flagcnt,
        float* __restrict__ out) {
    __shared__ short8 BT[4096];                // 64 KB: 2 bufs x (1024 hi | 1024 lo)

    const int tid  = threadIdx.x;
    const int lane = tid & 63;
    const int w    = tid >> 6;                 // wave 0..1
    const int l15  = lane & 15;
    const int lg   = lane >> 4;
    const int fb0  = blockIdx.x * 4 + w * 2;   // wave's first 16-row frag block

    const short8* Gh = (const short8*)ehi;
    const short8* Gl = (const short8*)elo;
    float* zfill = out + (size_t)blockIdx.x * 262144;   // zero region [0,134217728)

    // ---- prologue: read z rows, split hi/lo in-register -> A-frags (once) ----
    short8 ah[2][8], al[2][8];
    #pragma unroll
    for (int mi = 0; mi < 2; mi++) {
        int row = (fb0 + mi) * 16 + l15;
        const float* zr = z + (size_t)row * E_DIM + lg * 8;
        #pragma unroll
        for (int kt = 0; kt < 8; kt++) {
            float4 v0 = *(const float4*)(zr + kt * 32);
            float4 v1 = *(const float4*)(zr + kt * 32 + 4);
            float v[8] = {v0.x, v0.y, v0.z, v0.w, v1.x, v1.y, v1.z, v1.w};
            short8 h8, l8;
            #pragma unroll
            for (int t = 0; t < 8; t++) {
                unsigned short h = bfr(v[t]);
                h8[t] = (short)h;
                l8[t] = (short)bfr(v[t] - bf2f(h));
            }
            ah[mi][kt] = h8;
            al[mi][kt] = l8;
        }
    }

    float czs[8];
    #pragma unroll
    for (int mi = 0; mi < 2; mi++)
        #pragma unroll
        for (int qi = 0; qi < 4; qi++)
            czs[mi * 4 + qi] = znf[(fb0 + mi) * 16 + lg * 4 + qi];

    unsigned long long K1[8];
    float Qf[8];
    #pragma unroll
    for (int s = 0; s < 8; s++) { K1[s] = ~0ull; Qf[s] = __uint_as_float(0x7F800000u); }

    // stage 32-j tile t into buffer b: 1024 hi + 1024 lo short8, 8+8 per wave
    auto stage = [&](int t, int b) {
        const short8* sh = Gh + (size_t)t * 1024;
        const short8* sl = Gl + (size_t)t * 1024;
        short8* dh = &BT[b * 2048];
        short8* dl = &BT[b * 2048 + 1024];
        #pragma unroll
        for (int i = 0; i < 8; i++) {
            int c = (w * 8 + i) * 64;          // chunk base (short8 units), wave-uniform
            GLOAD_LDS16(sh + c + lane, dh + c);
            GLOAD_LDS16(sl + c + lane, dl + c);
        }
    };

#define LOADB(BH, BL, KT)                                                     \
    _Pragma("unroll")                                                         \
    for (int p = 0; p < 2; p++) {                                             \
        BH[p] = Bc_h[p * 512 + (KT) * 64 + lane];                             \
        BL[p] = Bc_l[p * 512 + (KT) * 64 + lane];                             \
    }
#define DOMFMA(BH, BL, KT)                                                    \
    _Pragma("unroll")                                                         \
    for (int p = 0; p < 2; p++) {                                             \
        _Pragma("unroll")                                                     \
        for (int mi = 0; mi < 2; mi++) {                                      \
            acc[mi][p] = __builtin_amdgcn_mfma_f32_16x16x32_bf16(ah[mi][KT], BH[p], acc[mi][p], 0, 0, 0); \
            acc[mi][p] = __builtin_amdgcn_mfma_f32_16x16x32_bf16(al[mi][KT], BH[p], acc[mi][p], 0, 0, 0); \
            acc[mi][p] = __builtin_amdgcn_mfma_f32_16x16x32_bf16(ah[mi][KT], BL[p], acc[mi][p], 0, 0, 0); \
        }                                                                     \
    }

    int cur = 0;
    stage(0, 0);
    for (int t = 0; t < 128; ++t) {
        __syncthreads();                       // drains stage of buf[cur] (2 waves only)
        if (t + 1 < 128) stage(t + 1, cur ^ 1);// async: flies during compute

        // ---- fused one-hot zero-fill: 8 KB/block/tile on the idle write path
        {
            f32x4 zv4 = {0.f, 0.f, 0.f, 0.f};
            float* dst = zfill + (size_t)t * 2048 + tid * 4;
            #pragma unroll
            for (int i = 0; i < 4; i++)
                __builtin_nontemporal_store(zv4, (f32x4*)(dst + i * 512));
        }

        const short8* Bc_h = &BT[cur * 2048];
        const short8* Bc_l = &BT[cur * 2048 + 1024];

        f32x4 acc[2][2];
        #pragma unroll
        for (int mi = 0; mi < 2; mi++) {
            acc[mi][0] = (f32x4){0.f, 0.f, 0.f, 0.f};
            acc[mi][1] = (f32x4){0.f, 0.f, 0.f, 0.f};
        }

        // 2-deep kt pipeline
        short8 bhA[2], blA[2], bhB[2], blB[2];
        LOADB(bhA, blA, 0)
        LOADB(bhB, blB, 1)
        DOMFMA(bhA, blA, 0) LOADB(bhA, blA, 2)
        DOMFMA(bhB, blB, 1) LOADB(bhB, blB, 3)
        DOMFMA(bhA, blA, 2) LOADB(bhA, blA, 4)
        DOMFMA(bhB, blB, 3) LOADB(bhB, blB, 5)
        DOMFMA(bhA, blA, 4) LOADB(bhA, blA, 6)
        DOMFMA(bhB, blB, 5) LOADB(bhB, blB, 7)
        DOMFMA(bhA, blA, 6)
        DOMFMA(bhB, blB, 7)

        #pragma unroll
        for (int p = 0; p < 2; p++) {
            int j = t * 32 + p * 16 + l15;
            float Ce = enf[j];
            #pragma unroll
            for (int mi = 0; mi < 2; mi++) {
                #pragma unroll
                for (int qi = 0; qi < 4; qi++) {
                    int s = mi * 4 + qi;
                    float av = acc[mi][p][qi];
                    float A  = czs[s] + Ce;                 // fl32(Cz+Ce)
                    float qv = fmaf(-2.0f, av, A);          // fl32(A-2acc)
                    unsigned long long kk =
                        ((unsigned long long)f2sort(qv) << 32) | (unsigned int)j;
                    if (kk < K1[s]) K1[s] = kk;
                    float res = (A - qv) - 2.0f * av;       // exact rounding residue
                    float u = __uint_as_float(__float_as_uint(qv) & 0x7F800000u)
                              * 1.1920929e-7f;              // ulp(qv)
                    if (fabsf(res) > fmaf(0.5f, u, -1.5e-7f))
                        Qf[s] = fminf(Qf[s], qv);
                }
            }
        }
        cur ^= 1;
    }
#undef LOADB
#undef DOMFMA

    // ---- final: reduce over l15 lanes; waves own disjoint rows ----
    #pragma unroll
    for (int s = 0; s < 8; s++) {
        unsigned long long K = K1[s];
        float Q = Qf[s];
        #pragma unroll
        for (int off = 1; off < 16; off <<= 1) {
            unsigned long long ok = __shfl_xor(K, off);
            float oq = __shfl_xor(Q, off);
            if (ok < K) K = ok;
            Q = fminf(Q, oq);
        }
        if (l15 == 0) {
            int row = blockIdx.x * 64 + w * 32 + (s >> 2) * 16 + lg * 4 + (s & 3);
            idx[row] = (int)(K & 0xFFFFFFFFull);
            float qwin = sort2f((unsigned int)(K >> 32));
            float u = __uint_as_float(__float_as_uint(qwin) & 0x7F800000u) * 1.1920929e-7f;
            if (Q <= fmaf(2.0f, u, qwin)) {    // fragile candidate within 2 grid steps
                int pp = atomicAdd(flagcnt, 1);
                flaglist[pp] = row;
            }
        }
    }
}

// ---------- kernel 4: exact np-replica repair, j-QUARTERED ----------
// ascending-k single-acc f32 fma chain; q = fl32(fl32(Cz+Ce) - 2*acc).
__global__ __launch_bounds__(256) void k_repair(const float* __restrict__ z,
                                                const float* __restrict__ emb,
                                                const float* __restrict__ enf,
                                                const float* __restrict__ znf,
                                                const int* __restrict__ flagcnt,
                                                const int* __restrict__ flaglist,
                                                unsigned long long* __restrict__ kpart) {
    __shared__ float zr[8][E_DIM];
    __shared__ unsigned long long redk[4][8];   // [wave][row]
    const int tid = threadIdx.x;
    const int cnt = flagcnt[0];
    const int oct = blockIdx.x >> 2;            // 0..255
    const int qd  = blockIdx.x & 3;             // j-quarter

    for (int base = oct * 8; base < cnt; base += 2048) {
        __syncthreads();                         // protect zr/redk reuse
        int gr[8];
        #pragma unroll
        for (int r = 0; r < 8; r++) {
            int fi = base + r;
            gr[r] = flaglist[fi < cnt ? fi : base];
        }
        for (int i = tid; i < 8 * 64; i += 256) {
            int r = i >> 6, c4 = i & 63;
            *(float4*)&zr[r][c4 * 4] = *(const float4*)(z + (size_t)gr[r] * E_DIM + c4 * 4);
        }
        __syncthreads();

        float Cz[8];
        #pragma unroll
        for (int r = 0; r < 8; r++) Cz[r] = znf[gr[r]];

        unsigned long long bk[8];
        #pragma unroll
        for (int r = 0; r < 8; r++) bk[r] = ~0ull;

        #pragma unroll
        for (int g = 0; g < 2; g++) {
            const int j0 = qd * 1024 + g * 512 + tid;   // streams j0, j0+256
            const float* e0 = emb + (size_t)(j0      ) * E_DIM;
            const float* e1 = emb + (size_t)(j0 + 256) * E_DIM;
            float a[8][2];
            #pragma unroll
            for (int r = 0; r < 8; r++) { a[r][0] = 0.0f; a[r][1] = 0.0f; }

            #pragma unroll 4
            for (int k4 = 0; k4 < 64; k4++) {
                float4 v0 = *(const float4*)(e0 + k4 * 4);
                float4 v1 = *(const float4*)(e1 + k4 * 4);
                #pragma unroll
                for (int r = 0; r < 8; r++) {
                    float4 zq = *(const float4*)&zr[r][k4 * 4];
                    a[r][0] = fmaf(zq.x, v0.x, a[r][0]); a[r][0] = fmaf(zq.y, v0.y, a[r][0]);
                    a[r][0] = fmaf(zq.z, v0.z, a[r][0]); a[r][0] = fmaf(zq.w, v0.w, a[r][0]);
                    a[r][1] = fmaf(zq.x, v1.x, a[r][1]); a[r][1] = fmaf(zq.y, v1.y, a[r][1]);
                    a[r][1] = fmaf(zq.z, v1.z, a[r][1]); a[r][1] = fmaf(zq.w, v1.w, a[r][1]);
                }
            }
            float en0 = enf[j0], en1 = enf[j0 + 256];
            #pragma unroll
            for (int r = 0; r < 8; r++) {
                float q0 = (Cz[r] + en0) - 2.0f * a[r][0];
                float q1 = (Cz[r] + en1) - 2.0f * a[r][1];
                unsigned long long k;
                k = ((unsigned long long)f2sort(q0) << 32) | (unsigned int)(j0      ); if (k < bk[r]) bk[r] = k;
                k = ((unsigned long long)f2sort(q1) << 32) | (unsigned int)(j0 + 256); if (k < bk[r]) bk[r] = k;
            }
        }

        const int w = tid >> 6;
        #pragma unroll
        for (int r = 0; r < 8; r++) {
            unsigned long long K = bk[r];
            #pragma unroll
            for (int off = 1; off < 64; off <<= 1) {
                unsigned long long ok = __shfl_xor(K, off);
                if (ok < K) K = ok;
            }
            if ((tid & 63) == 0) redk[w][r] = K;
        }
        __syncthreads();
        if (tid < 8 && base + tid < cnt) {
            unsigned long long K = redk[0][tid];
            #pragma unroll
            for (int wv = 1; wv < 4; wv++)
                if (redk[wv][tid] < K) K = redk[wv][tid];
            kpart[(size_t)(base + tid) * 4 + qd] = K;
        }
    }
}

// ---------- kernel 5: reduce j-quarters -> idx ----------
__global__ __launch_bounds__(256) void k_fin(const int* __restrict__ flagcnt,
                                             const int* __restrict__ flaglist,
                                             const unsigned long long* __restrict__ kpart,
                                             int* __restrict__ idx) {
    const int cnt = flagcnt[0];
    for (int fi = blockIdx.x * 256 + threadIdx.x; fi < cnt; fi += gridDim.x * 256) {
        unsigned long long K = kpart[(size_t)fi * 4];
        #pragma unroll
        for (int qd = 1; qd < 4; qd++) {
            unsigned long long k2 = kpart[(size_t)fi * 4 + qd];
            if (k2 < K) K = k2;
        }
        idx[flaglist[fi]] = (int)(K & 0xFFFFFFFFull);
    }
}

// ---------- kernel 6: epilogue (zeros already written by k_screen) ----------
// d_out FLOAT32: [loss(1) | one-hot(32768*4096) | z_q_st(32768*256) |
//                 emb(4096*256) | indices(32768)]
__global__ __launch_bounds__(256) void k_epilogue(const float* __restrict__ z,
                                                  const float* __restrict__ emb,
                                                  const int* __restrict__ idx,
                                                  float* __restrict__ out,
                                                  double* __restrict__ rowloss) {
    const int row  = blockIdx.x * 4 + (threadIdx.x >> 6);
    const int lane = threadIdx.x & 63;
    const int j    = idx[row];
    float4 zv = *(const float4*)(z   + (size_t)row * E_DIM + lane * 4);
    float4 ev = *(const float4*)(emb + (size_t)j   * E_DIM + lane * 4);

    // z_q_st = fl32(z + fl32(z_q - z))
    float4 st;
    st.x = zv.x + (ev.x - zv.x);
    st.y = zv.y + (ev.y - zv.y);
    st.z = zv.z + (ev.z - zv.z);
    st.w = zv.w + (ev.w - zv.w);
    const size_t zq0 = 1ull + (size_t)N_ROWS * N_E;
    *(float4*)(out + zq0 + (size_t)row * E_DIM + lane * 4) = st;

    double dx = (double)ev.x - zv.x, dy = (double)ev.y - zv.y;
    double dz = (double)ev.z - zv.z, dw = (double)ev.w - zv.w;
    double s = dx * dx + dy * dy + dz * dz + dw * dw;
    #pragma unroll
    for (int off = 1; off < 64; off <<= 1) s += __shfl_xor(s, off);

    if (lane == 0) {
        rowloss[row] = s;
        // screen zeroed floats [0,134217728); the last one-hot cell
        // (row 32767, col 4095) sits at 134217728 -> cover it here.
        if (row == N_ROWS - 1 && j != N_E - 1)
            out[1ull + (size_t)row * N_E + (N_E - 1)] = 0.0f;
        out[1ull + (size_t)row * N_E + j] = 1.0f;
        const size_t ix0 = 1ull + (size_t)N_ROWS * N_E + (size_t)N_ROWS * E_DIM
                         + (size_t)N_E * E_DIM;
        out[ix0 + row] = (float)j;
    }
}

// ---------- kernel 7: deterministic loss reduce ----------
__global__ __launch_bounds__(256) void k_loss(const double* __restrict__ rowloss,
                                              float* __restrict__ out) {
    __shared__ double sm[256];
    double s = 0.0;
    for (int i = threadIdx.x; i < N_ROWS; i += 256) s += rowloss[i];
    sm[threadIdx.x] = s;
    __syncthreads();
    for (int h = 128; h > 0; h >>= 1) {
        if (threadIdx.x < h) sm[threadIdx.x] += sm[threadIdx.x + h];
        __syncthreads();
    }
    if (threadIdx.x == 0)
        out[0] = (float)(sm[0] / ((double)N_ROWS * (double)E_DIM));
}

extern "C" void kernel_launch(void* const* d_in, const int* in_sizes, int n_in,
                              void* d_out, int out_size, void* d_ws, size_t ws_size,
                              hipStream_t stream) {
    const float* z   = (const float*)d_in[0];
    const float* emb = (const float*)d_in[1];
    float* out = (float*)d_out;

    // workspace layout (disjoint, 16B-aligned)
    char* ws = (char*)d_ws;
    float*              enf      = (float*)(ws + 0);                 // 16 KB  -> 16384
    float*              znf      = (float*)(ws + 16384);             // 128 KB -> 147456
    int*                idx      = (int*)(ws + 147456);              // 128 KB -> 278528
    int*                flagcnt  = (int*)(ws + 278528);              // 128 B  -> 278656
    int*                flaglist = (int*)(ws + 278656);              // 128 KB -> 409728
    double*             rowloss  = (double*)(ws + 409728);           // 256 KB -> 671872
    unsigned long long* kpart    = (unsigned long long*)(ws + 671872);// 1 MB  -> 1720320
    unsigned short*     ehi      = (unsigned short*)(ws + 1720320);  // 2 MB   -> 3817472
    unsigned short*     elo      = (unsigned short*)(ws + 3817472);  // 2 MB   -> 5914624

    hipMemsetAsync(flagcnt, 0, sizeof(int), stream);

    // emb passthrough chunk: exact d2d copy
    const size_t emb0 = 1ull + (size_t)N_ROWS * N_E + (size_t)N_ROWS * E_DIM;
    hipMemcpyAsync(out + emb0, emb, (size_t)N_E * E_DIM * sizeof(float),
                   hipMemcpyDeviceToDevice, stream);

    k_rownorm <<<N_E / 4, 256, 0, stream>>>(emb, enf);
    k_rownorm <<<N_ROWS / 4, 256, 0, stream>>>(z, znf);
    k_split   <<<N_E / 8, 256, 0, stream>>>(emb, ehi, elo);
    k_screen  <<<512, 128, 0, stream>>>(z, ehi, elo, enf, znf,
                                        idx, flaglist, flagcnt, out);
    k_repair  <<<1024, 256, 0, stream>>>(z, emb, enf, znf, flagcnt, flaglist, kpart);
    k_fin     <<<32, 256, 0, stream>>>(flagcnt, flaglist, kpart, idx);
    k_epilogue<<<N_ROWS / 4, 256, 0, stream>>>(z, emb, idx, out, rowloss);
    k_loss    <<<1, 256, 0, stream>>>(rowloss, out);
}